// Round 12
// baseline (1798.528 us; speedup 1.0000x reference)
//
#include <hip/hip_runtime.h>
#include <hip/hip_cooperative_groups.h>
#include <math.h>

namespace cg = cooperative_groups;

#define NB 4
#define DIMM 256
#define DSTATE 16
#define DCONV 4
#define DIN 512
#define DTRANK 16
#define BB 16
#define LL 512
#define TT (BB * LL)            // 8192 tokens
#define XZ_DIM (2 * DIN)        // 1024
#define DBC_DIM (DTRANK + 2 * DSTATE)  // 48
#define NC 32                   // scan chunks
#define CHUNK (LL / NC)         // 16

__device__ __forceinline__ unsigned short f2bf(float f) {
    union { float f; unsigned int u; } v; v.f = f;
    unsigned int r = v.u + 0x7fff + ((v.u >> 16) & 1);
    return (unsigned short)(r >> 16);
}
__device__ __forceinline__ float bf2f(unsigned short u) {
    union { unsigned int i; float f; } v; v.i = ((unsigned int)u) << 16;
    return v.f;
}

// ---------------- fp32 -> bf16 weight convert (all three, one dispatch) ------
__global__ __launch_bounds__(256) void cvt3_kernel(const float* __restrict__ s1,
                                                   unsigned short* __restrict__ d1, int n1,
                                                   const float* __restrict__ s2,
                                                   unsigned short* __restrict__ d2, int n2,
                                                   const float* __restrict__ s3,
                                                   unsigned short* __restrict__ d3, int n3) {
    int stride = gridDim.x * 256;
    for (int i = blockIdx.x * 256 + threadIdx.x; i < n1; i += stride) {
        float4 v = ((const float4*)s1)[i];
        ushort4 o; o.x = f2bf(v.x); o.y = f2bf(v.y); o.z = f2bf(v.z); o.w = f2bf(v.w);
        ((ushort4*)d1)[i] = o;
    }
    for (int i = blockIdx.x * 256 + threadIdx.x; i < n2; i += stride) {
        float4 v = ((const float4*)s2)[i];
        ushort4 o; o.x = f2bf(v.x); o.y = f2bf(v.y); o.z = f2bf(v.z); o.w = f2bf(v.w);
        ((ushort4*)d2)[i] = o;
    }
    for (int i = blockIdx.x * 256 + threadIdx.x; i < n3; i += stride) {
        float4 v = ((const float4*)s3)[i];
        ushort4 o; o.x = f2bf(v.x); o.y = f2bf(v.y); o.z = f2bf(v.z); o.w = f2bf(v.w);
        ((ushort4*)d3)[i] = o;
    }
}

// ---------------- Fused LayerNorm + in_proj (128x128, padded LDS) ------------
#define GBM2 128
#define GBN2 128
#define GBK2 32
#define LDW2 (GBK2 + 8)   // 40 ushorts
__global__ __launch_bounds__(256) void ln_inproj(const float* __restrict__ x,
                                                 const float* __restrict__ lnw,
                                                 const float* __restrict__ lnb,
                                                 const unsigned short* __restrict__ Bw,
                                                 const float* __restrict__ bias,
                                                 unsigned short* __restrict__ C1b,
                                                 unsigned short* __restrict__ C2b,
                                                 int nsplit, int ldc) {
    using short8  = __attribute__((ext_vector_type(8))) short;
    using floatx4 = __attribute__((ext_vector_type(4))) float;
    __shared__ __align__(16) unsigned short As[GBM2 * LDW2];
    __shared__ __align__(16) unsigned short Bs[GBN2 * LDW2];
    __shared__ float muS[GBM2], rsS[GBM2], lwS[DIMM], lbS[DIMM];

    int tid  = threadIdx.x;
    int m0   = blockIdx.y * GBM2;
    int n0   = blockIdx.x * GBN2;
    int w    = tid >> 6;
    int lane = tid & 63;
    int wm   = (w & 1) * 64;
    int wn   = (w >> 1) * 64;
    int lr   = lane & 15;
    int quad = lane >> 4;

    {
        int r = tid >> 1;
        int seg = (tid & 1) * 128;
        const float4* xr = (const float4*)(x + (size_t)(m0 + r) * DIMM + seg);
        float s = 0.0f, s2 = 0.0f;
#pragma unroll
        for (int i = 0; i < 32; ++i) {
            float4 v = xr[i];
            s  += v.x + v.y + v.z + v.w;
            s2 += v.x * v.x + v.y * v.y + v.z * v.z + v.w * v.w;
        }
        s  += __shfl_xor(s, 1);
        s2 += __shfl_xor(s2, 1);
        if ((tid & 1) == 0) {
            float mu  = s * (1.0f / DIMM);
            float var = s2 * (1.0f / DIMM) - mu * mu;
            muS[r] = mu;
            rsS[r] = rsqrtf(var + 1e-5f);
        }
        lwS[tid] = lnw[tid];
        lbS[tid] = lnb[tid];
    }
    __syncthreads();

    floatx4 acc[4][4] = {};

    int ar = tid >> 1;
    int ak = (tid & 1) * 16;

    for (int k0 = 0; k0 < DIMM; k0 += GBK2) {
        {
            float mu = muS[ar], rs = rsS[ar];
            const float4* src = (const float4*)(x + (size_t)(m0 + ar) * DIMM + k0 + ak);
            unsigned short tmp[16];
#pragma unroll
            for (int q = 0; q < 4; ++q) {
                float4 v = src[q];
                int kk = k0 + ak + q * 4;
                tmp[q * 4 + 0] = f2bf((v.x - mu) * rs * lwS[kk + 0] + lbS[kk + 0]);
                tmp[q * 4 + 1] = f2bf((v.y - mu) * rs * lwS[kk + 1] + lbS[kk + 1]);
                tmp[q * 4 + 2] = f2bf((v.z - mu) * rs * lwS[kk + 2] + lbS[kk + 2]);
                tmp[q * 4 + 3] = f2bf((v.w - mu) * rs * lwS[kk + 3] + lbS[kk + 3]);
            }
            *(int4*)&As[ar * LDW2 + ak]     = *(const int4*)&tmp[0];
            *(int4*)&As[ar * LDW2 + ak + 8] = *(const int4*)&tmp[8];
        }
        {
            const unsigned short* src = &Bw[(size_t)(n0 + ar) * DIMM + k0 + ak];
            int4 b0 = *(const int4*)(src);
            int4 b1 = *(const int4*)(src + 8);
            *(int4*)&Bs[ar * LDW2 + ak]     = b0;
            *(int4*)&Bs[ar * LDW2 + ak + 8] = b1;
        }
        __syncthreads();
        short8 af[4], bf[4];
#pragma unroll
        for (int i = 0; i < 4; ++i)
            af[i] = *(const short8*)&As[(wm + i * 16 + lr) * LDW2 + quad * 8];
#pragma unroll
        for (int j = 0; j < 4; ++j)
            bf[j] = *(const short8*)&Bs[(wn + j * 16 + lr) * LDW2 + quad * 8];
#pragma unroll
        for (int i = 0; i < 4; ++i)
#pragma unroll
            for (int j = 0; j < 4; ++j)
                acc[i][j] = __builtin_amdgcn_mfma_f32_16x16x32_bf16(af[i], bf[j], acc[i][j], 0, 0, 0);
        __syncthreads();
    }

#pragma unroll
    for (int j = 0; j < 4; ++j) {
        int cn = n0 + wn + j * 16 + lr;
        float bb = bias[cn];
        unsigned short* dst = (cn < nsplit) ? C1b : C2b;
        int col = (cn < nsplit) ? cn : cn - nsplit;
#pragma unroll
        for (int i = 0; i < 4; ++i)
#pragma unroll
            for (int r = 0; r < 4; ++r) {
                int cm = m0 + wm + i * 16 + quad * 4 + r;
                dst[(size_t)cm * ldc + col] = f2bf(acc[i][j][r] + bb);
            }
    }
}

// ---------------- bf16 MFMA NT GEMM (generic, proven) ------------------------
#define TBM 128
#define TBN 64
#define TBK 32
#define LDKW (TBK + 8)
__global__ __launch_bounds__(256) void gemm_bf16(const unsigned short* __restrict__ A, int lda,
                                                 const unsigned short* __restrict__ Bw, int ldb,
                                                 const float* __restrict__ bias,
                                                 const float* __restrict__ resid,
                                                 float* __restrict__ C,
                                                 unsigned short* __restrict__ C1b,
                                                 unsigned short* __restrict__ C2b, int nsplit,
                                                 int ldc, int N, int K) {
    using short8  = __attribute__((ext_vector_type(8))) short;
    using floatx4 = __attribute__((ext_vector_type(4))) float;
    __shared__ __align__(16) unsigned short As[TBM * LDKW];
    __shared__ __align__(16) unsigned short Bs[TBN * LDKW];

    int tid  = threadIdx.x;
    int m0   = blockIdx.y * TBM;
    int n0   = blockIdx.x * TBN;
    int w    = tid >> 6;
    int lane = tid & 63;
    int wm   = (w & 1) * 64;
    int wn   = (w >> 1) * 32;
    int lr   = lane & 15;
    int quad = lane >> 4;

    floatx4 acc[4][2] = {};

    int ar = tid >> 1;
    int ak = (tid & 1) * 16;
    int br = tid >> 2;
    int bk = (tid & 3) * 8;

    for (int k0 = 0; k0 < K; k0 += TBK) {
        {
            const unsigned short* src = &A[(size_t)(m0 + ar) * lda + k0 + ak];
            int4 a0 = *(const int4*)(src);
            int4 a1 = *(const int4*)(src + 8);
            *(int4*)&As[ar * LDKW + ak]     = a0;
            *(int4*)&As[ar * LDKW + ak + 8] = a1;
        }
        {
            int gn = n0 + br;
            int4 b0 = make_int4(0, 0, 0, 0);
            if (gn < N) b0 = *(const int4*)&Bw[(size_t)gn * ldb + k0 + bk];
            *(int4*)&Bs[br * LDKW + bk] = b0;
        }
        __syncthreads();
        short8 af[4], bf[2];
#pragma unroll
        for (int i = 0; i < 4; ++i)
            af[i] = *(const short8*)&As[(wm + i * 16 + lr) * LDKW + quad * 8];
#pragma unroll
        for (int j = 0; j < 2; ++j)
            bf[j] = *(const short8*)&Bs[(wn + j * 16 + lr) * LDKW + quad * 8];
#pragma unroll
        for (int i = 0; i < 4; ++i)
#pragma unroll
            for (int j = 0; j < 2; ++j)
                acc[i][j] = __builtin_amdgcn_mfma_f32_16x16x32_bf16(af[i], bf[j], acc[i][j], 0, 0, 0);
        __syncthreads();
    }

#pragma unroll
    for (int j = 0; j < 2; ++j) {
        int cn = n0 + wn + j * 16 + lr;
        if (cn < N) {
            float bb = bias ? bias[cn] : 0.0f;
            if (C1b) {
                unsigned short* dst = (cn < nsplit) ? C1b : C2b;
                int col = (cn < nsplit) ? cn : cn - nsplit;
#pragma unroll
                for (int i = 0; i < 4; ++i)
#pragma unroll
                    for (int r = 0; r < 4; ++r) {
                        int cm = m0 + wm + i * 16 + quad * 4 + r;
                        dst[(size_t)cm * ldc + col] = f2bf(acc[i][j][r] + bb);
                    }
            } else {
#pragma unroll
                for (int i = 0; i < 4; ++i)
#pragma unroll
                    for (int r = 0; r < 4; ++r) {
                        int cm = m0 + wm + i * 16 + quad * 4 + r;
                        float v = acc[i][j][r] + bb;
                        if (resid) v += resid[(size_t)cm * ldc + cn];
                        C[(size_t)cm * ldc + cn] = v;
                    }
            }
        }
    }
}

// ---------------- Depthwise causal conv (4-tap) + SiLU, bf16 in/out ----------
__global__ __launch_bounds__(256) void conv_silu(const unsigned short* __restrict__ Xb,
                                                 const float* __restrict__ cw,
                                                 const float* __restrict__ cb,
                                                 unsigned short* __restrict__ xcb) {
    int idx = blockIdx.x * blockDim.x + threadIdx.x;
    int d = idx & (DIN - 1);
    int t = idx >> 9;
    int l = t & (LL - 1);
    int bq = t >> 9;
    float acc = cb[d];
#pragma unroll
    for (int k = 0; k < DCONV; ++k) {
        int ls = l - (DCONV - 1) + k;
        if (ls >= 0) acc += cw[d * DCONV + k] * bf2f(Xb[(size_t)(bq * LL + ls) * DIN + d]);
    }
    float v = acc / (1.0f + __expf(-acc));
    xcb[(size_t)t * DIN + d] = f2bf(v);
}

// ---------------- dt = softplus(dbc[:, :16] @ dtw^T + dtb) -> bf16 -----------
__global__ __launch_bounds__(256) void dt_kernel(const float* __restrict__ dbc,
                                                 const float* __restrict__ dtw,
                                                 const float* __restrict__ dtbias,
                                                 unsigned short* __restrict__ dtout) {
    int idx = blockIdx.x * blockDim.x + threadIdx.x;
    int d = idx & (DIN - 1);
    int t = idx >> 9;
    float a = dtbias[d];
    const float4* wv = (const float4*)(dtw + d * DTRANK);
    const float* dr = dbc + (size_t)t * DBC_DIM;
#pragma unroll
    for (int q = 0; q < 4; ++q) {
        float4 w4 = wv[q];
        a += w4.x * dr[q * 4 + 0] + w4.y * dr[q * 4 + 1] +
             w4.z * dr[q * 4 + 2] + w4.w * dr[q * 4 + 3];
    }
    float sp = (a > 20.0f) ? a : log1pf(__expf(a));
    dtout[(size_t)t * DIN + d] = f2bf(sp);
}

// ---------------- Cooperative fused scan: p1 + p2 + p3, one dispatch ---------
// 1024 blocks (4/CU co-resident). rb = b*64 + ch*4 + dq; block handles chunks
// c = ch*2 + {0,1}. Thread = 128 d x 2 state-halves.
__global__ __launch_bounds__(256, 4) void scan_coop(const unsigned short* __restrict__ xcb,
                                                    const unsigned short* __restrict__ dtb,
                                                    const unsigned short* __restrict__ Zb,
                                                    const float* __restrict__ dbc,
                                                    const float* __restrict__ A_log,
                                                    const float* __restrict__ Dp,
                                                    float* __restrict__ S,
                                                    float* __restrict__ H,
                                                    unsigned short* __restrict__ gb) {
    cg::grid_group gg = cg::this_grid();
    __shared__ float LB[CHUNK * DBC_DIM];

    int rb = blockIdx.x;
    int dq = rb & 3;
    int ch = (rb >> 2) & 15;
    int b  = rb >> 6;
    int dloc = threadIdx.x >> 1;
    int sh   = threadIdx.x & 1;
    int d  = dq * 128 + dloc;
    int n0 = sh * 8;

    float a[8];
    {
        const float4* ar = (const float4*)(A_log + d * DSTATE + n0);
        float4 v0 = ar[0], v1 = ar[1];
        a[0] = -__expf(v0.x); a[1] = -__expf(v0.y); a[2] = -__expf(v0.z); a[3] = -__expf(v0.w);
        a[4] = -__expf(v1.x); a[5] = -__expf(v1.y); a[6] = -__expf(v1.z); a[7] = -__expf(v1.w);
    }

    // ---- phase 1: two chunks ----
#pragma unroll
    for (int r = 0; r < 2; ++r) {
        int c = ch * 2 + r;
        int base = b * LL + c * CHUNK;
        __syncthreads();
        for (int i = threadIdx.x; i < CHUNK * DBC_DIM / 4; i += 256)
            ((float4*)LB)[i] = ((const float4*)(dbc + (size_t)base * DBC_DIM))[i];
        __syncthreads();

        float h[8];
#pragma unroll
        for (int j = 0; j < 8; ++j) h[j] = 0.0f;
        float Ssum = 0.0f;
        float u   = bf2f(xcb[(size_t)base * DIN + d]);
        float dtv = bf2f(dtb[(size_t)base * DIN + d]);
#pragma unroll 4
        for (int s = 0; s < CHUNK; ++s) {
            float nu  = bf2f(xcb[(size_t)(base + s + 1) * DIN + d]);
            float ndt = bf2f(dtb[(size_t)(base + s + 1) * DIN + d]);
            const float* row = &LB[s * DBC_DIM];
            float4 b0 = *(const float4*)&row[DTRANK + n0];
            float4 b1 = *(const float4*)&row[DTRANK + n0 + 4];
            const float btv[8] = {b0.x, b0.y, b0.z, b0.w, b1.x, b1.y, b1.z, b1.w};
            Ssum += dtv;
            float wv = dtv * u;
#pragma unroll
            for (int j = 0; j < 8; ++j) {
                float dA = __expf(dtv * a[j]);
                h[j] = dA * h[j] + wv * btv[j];
            }
            u = nu; dtv = ndt;
        }
        size_t sc = (size_t)b * NC + c;
        if (sh == 0) S[sc * DIN + d] = Ssum;
#pragma unroll
        for (int j = 0; j < 8; ++j) H[(sc * DIN + d) * 16 + n0 + j] = h[j];
    }

    gg.sync();

    // ---- phase 2: 512 blocks combine serially over chunks ----
    if (rb < 512) {
        int idx = rb * 256 + threadIdx.x;   // BB*DIN*16 = 131072
        int n2 = idx & 15;
        int d2 = (idx >> 4) & (DIN - 1);
        int b2 = idx >> 13;
        float a2 = -__expf(A_log[d2 * DSTATE + n2]);
        float h2 = 0.0f;
#pragma unroll
        for (int c = 0; c < NC; ++c) {
            size_t sc = (size_t)b2 * NC + c;
            float Sv = S[sc * DIN + d2];
            size_t q = (sc * DIN + d2) * 16 + n2;
            float Hc = H[q];
            H[q] = h2;
            h2 = __expf(a2 * Sv) * h2 + Hc;
        }
    }

    gg.sync();

    // ---- phase 3: two chunks, h0 = carry; fused g = y*silu(z) -> bf16 ----
    float Dd = Dp[d];
#pragma unroll
    for (int r = 0; r < 2; ++r) {
        int c = ch * 2 + r;
        int base = b * LL + c * CHUNK;
        size_t sc = (size_t)b * NC + c;
        __syncthreads();
        for (int i = threadIdx.x; i < CHUNK * DBC_DIM / 4; i += 256)
            ((float4*)LB)[i] = ((const float4*)(dbc + (size_t)base * DBC_DIM))[i];
        __syncthreads();

        float h[8];
#pragma unroll
        for (int j = 0; j < 8; ++j) h[j] = H[(sc * DIN + d) * 16 + n0 + j];

        float u   = bf2f(xcb[(size_t)base * DIN + d]);
        float dtv = bf2f(dtb[(size_t)base * DIN + d]);
#pragma unroll 4
        for (int s = 0; s < CHUNK; ++s) {
            float nu  = bf2f(xcb[(size_t)(base + s + 1) * DIN + d]);
            float ndt = bf2f(dtb[(size_t)(base + s + 1) * DIN + d]);
            const float* row = &LB[s * DBC_DIM];
            float4 b0 = *(const float4*)&row[DTRANK + n0];
            float4 b1 = *(const float4*)&row[DTRANK + n0 + 4];
            float4 c0 = *(const float4*)&row[DTRANK + DSTATE + n0];
            float4 c1 = *(const float4*)&row[DTRANK + DSTATE + n0 + 4];
            const float btv[8] = {b0.x, b0.y, b0.z, b0.w, b1.x, b1.y, b1.z, b1.w};
            const float ctv[8] = {c0.x, c0.y, c0.z, c0.w, c1.x, c1.y, c1.z, c1.w};
            float wv = dtv * u;
            float y  = (sh == 0) ? u * Dd : 0.0f;
#pragma unroll
            for (int j = 0; j < 8; ++j) {
                float dA = __expf(dtv * a[j]);
                h[j] = dA * h[j] + wv * btv[j];
                y += h[j] * ctv[j];
            }
            y += __shfl_xor(y, 1);
            if (sh == 0) {
                float zf = bf2f(Zb[(size_t)(base + s) * DIN + d]);
                float g = y * (zf / (1.0f + __expf(-zf)));
                gb[(size_t)(base + s) * DIN + d] = f2bf(g);
            }
            u = nu; dtv = ndt;
        }
    }
}

extern "C" void kernel_launch(void* const* d_in, const int* in_sizes, int n_in,
                              void* d_out, int out_size, void* d_ws, size_t ws_size,
                              hipStream_t stream) {
    const float* x_in   = (const float*)d_in[0];
    const float* ln_w   = (const float*)d_in[1];
    const float* ln_b   = (const float*)d_in[2];
    const float* in_w   = (const float*)d_in[3];
    const float* in_b   = (const float*)d_in[4];
    const float* conv_w = (const float*)d_in[5];
    const float* conv_b = (const float*)d_in[6];
    const float* xp_w   = (const float*)d_in[7];
    const float* dt_w   = (const float*)d_in[8];
    const float* dt_b   = (const float*)d_in[9];
    const float* A_log  = (const float*)d_in[10];
    const float* Dp     = (const float*)d_in[11];
    const float* ow     = (const float*)d_in[12];
    float* out = (float*)d_out;

    const size_t M = 1048576;
    float* ws = (float*)d_ws;
    float* xbuf = ws;                              // [0,2M) fp32 layer io
    float* dbc = ws + 3 * M;                       // [3M,3.5M) fp32 TT*48
    unsigned short* Xb  = (unsigned short*)(ws + 4 * M);   // [4M,6M) bf16 TT*512
    unsigned short* Zb  = (unsigned short*)(ws + 6 * M);   // [6M,8M)
    unsigned short* xcb = (unsigned short*)(ws + 8 * M);   // [8M,10M)
    unsigned short* dtb = (unsigned short*)(ws + 10 * M);  // [10M,12M)
    unsigned short* gb  = (unsigned short*)(ws + 12 * M);  // [12M,14M)
    float* Hbuf = ws + 14 * M;                     // [14M,18M) BB*NC*DIN*16 = 4M
    float* Sbuf = ws + 18 * M;                     // [18M,18.25M)
    unsigned short* inwb = (unsigned short*)(ws + 18 * M + 262144);
    unsigned short* owb  = inwb + (size_t)NB * XZ_DIM * DIMM;
    unsigned short* xpwb = owb + (size_t)NB * DIMM * DIN;

    cvt3_kernel<<<256, 256, 0, stream>>>(
        in_w, inwb, NB * XZ_DIM * DIMM / 4,
        ow,   owb,  NB * DIMM * DIN / 4,
        xp_w, xpwb, NB * DBC_DIM * DIN / 4);

    for (int layer = 0; layer < NB; ++layer) {
        const float* xi = (layer == 0) ? x_in : xbuf;
        float* xo = (layer == NB - 1) ? out : xbuf;

        // fused LN + in_proj: both halves bf16 (X -> Xb, Z -> Zb)
        ln_inproj<<<dim3(XZ_DIM / GBN2, TT / GBM2), 256, 0, stream>>>(
            xi, ln_w + layer * DIMM, ln_b + layer * DIMM,
            inwb + (size_t)layer * XZ_DIM * DIMM, in_b + layer * XZ_DIM,
            Xb, Zb, DIN, DIN);

        conv_silu<<<(TT * DIN) / 256, 256, 0, stream>>>(
            Xb, conv_w + layer * DIN * DCONV, conv_b + layer * DIN, xcb);

        // x_proj: bf16 MFMA -> dbc fp32
        gemm_bf16<<<dim3(1, TT / TBM), 256, 0, stream>>>(
            xcb, DIN, xpwb + (size_t)layer * DBC_DIM * DIN, DIN,
            nullptr, nullptr, dbc, nullptr, nullptr, 0, DBC_DIM, DBC_DIM, DIN);

        dt_kernel<<<(TT * DIN) / 256, 256, 0, stream>>>(
            dbc, dt_w + (size_t)layer * DIN * DTRANK, dt_b + layer * DIN, dtb);

        // fused scan: one cooperative dispatch (p1 + p2 + p3)
        {
            const unsigned short* xcb_c = xcb;
            const unsigned short* dtb_c = dtb;
            const unsigned short* Zb_c  = Zb;
            const float* dbc_c = dbc;
            const float* Al  = A_log + (size_t)layer * DIN * DSTATE;
            const float* Dpl = Dp + layer * DIN;
            float* S_c = Sbuf;
            float* H_c = Hbuf;
            unsigned short* gb_c = gb;
            void* kargs[] = {(void*)&xcb_c, (void*)&dtb_c, (void*)&Zb_c,
                             (void*)&dbc_c, (void*)&Al, (void*)&Dpl,
                             (void*)&S_c, (void*)&H_c, (void*)&gb_c};
            hipLaunchCooperativeKernel((const void*)scan_coop, dim3(1024), dim3(256),
                                       kargs, 0, stream);
        }

        // out_proj: fp32 out + residual
        gemm_bf16<<<dim3(DIMM / TBN, TT / TBM), 256, 0, stream>>>(
            gb, DIN, owb + (size_t)layer * DIMM * DIN, DIN,
            nullptr, xi, xo, nullptr, nullptr, 0, DIMM, DIMM, DIN);
    }
}

// Round 13
// 702.723 us; speedup vs baseline: 2.5594x; 2.5594x over previous
//
#include <hip/hip_runtime.h>
#include <math.h>

#define NB 4
#define DIMM 256
#define DSTATE 16
#define DCONV 4
#define DIN 512
#define DTRANK 16
#define BB 16
#define LL 512
#define TT (BB * LL)            // 8192 tokens
#define XZ_DIM (2 * DIN)        // 1024
#define DBC_DIM (DTRANK + 2 * DSTATE)  // 48
#define NC 32                   // scan chunks
#define CHUNK (LL / NC)         // 16

__device__ __forceinline__ unsigned short f2bf(float f) {
    union { float f; unsigned int u; } v; v.f = f;
    unsigned int r = v.u + 0x7fff + ((v.u >> 16) & 1);
    return (unsigned short)(r >> 16);
}
__device__ __forceinline__ float bf2f(unsigned short u) {
    union { unsigned int i; float f; } v; v.i = ((unsigned int)u) << 16;
    return v.f;
}

// ---------------- fp32 -> bf16 weight convert (all three, one dispatch) ------
__global__ __launch_bounds__(256) void cvt3_kernel(const float* __restrict__ s1,
                                                   unsigned short* __restrict__ d1, int n1,
                                                   const float* __restrict__ s2,
                                                   unsigned short* __restrict__ d2, int n2,
                                                   const float* __restrict__ s3,
                                                   unsigned short* __restrict__ d3, int n3) {
    int stride = gridDim.x * 256;
    for (int i = blockIdx.x * 256 + threadIdx.x; i < n1; i += stride) {
        float4 v = ((const float4*)s1)[i];
        ushort4 o; o.x = f2bf(v.x); o.y = f2bf(v.y); o.z = f2bf(v.z); o.w = f2bf(v.w);
        ((ushort4*)d1)[i] = o;
    }
    for (int i = blockIdx.x * 256 + threadIdx.x; i < n2; i += stride) {
        float4 v = ((const float4*)s2)[i];
        ushort4 o; o.x = f2bf(v.x); o.y = f2bf(v.y); o.z = f2bf(v.z); o.w = f2bf(v.w);
        ((ushort4*)d2)[i] = o;
    }
    for (int i = blockIdx.x * 256 + threadIdx.x; i < n3; i += stride) {
        float4 v = ((const float4*)s3)[i];
        ushort4 o; o.x = f2bf(v.x); o.y = f2bf(v.y); o.z = f2bf(v.z); o.w = f2bf(v.w);
        ((ushort4*)d3)[i] = o;
    }
}

// ---------------- Fused LayerNorm + in_proj (128x128, padded LDS) ------------
#define GBM2 128
#define GBN2 128
#define GBK2 32
#define LDW2 (GBK2 + 8)   // 40 ushorts
__global__ __launch_bounds__(256) void ln_inproj(const float* __restrict__ x,
                                                 const float* __restrict__ lnw,
                                                 const float* __restrict__ lnb,
                                                 const unsigned short* __restrict__ Bw,
                                                 const float* __restrict__ bias,
                                                 unsigned short* __restrict__ C1b,
                                                 unsigned short* __restrict__ C2b,
                                                 int nsplit, int ldc) {
    using short8  = __attribute__((ext_vector_type(8))) short;
    using floatx4 = __attribute__((ext_vector_type(4))) float;
    __shared__ __align__(16) unsigned short As[GBM2 * LDW2];
    __shared__ __align__(16) unsigned short Bs[GBN2 * LDW2];
    __shared__ float muS[GBM2], rsS[GBM2], lwS[DIMM], lbS[DIMM];

    int tid  = threadIdx.x;
    int m0   = blockIdx.y * GBM2;
    int n0   = blockIdx.x * GBN2;
    int w    = tid >> 6;
    int lane = tid & 63;
    int wm   = (w & 1) * 64;
    int wn   = (w >> 1) * 64;
    int lr   = lane & 15;
    int quad = lane >> 4;

    {
        int r = tid >> 1;
        int seg = (tid & 1) * 128;
        const float4* xr = (const float4*)(x + (size_t)(m0 + r) * DIMM + seg);
        float s = 0.0f, s2 = 0.0f;
#pragma unroll
        for (int i = 0; i < 32; ++i) {
            float4 v = xr[i];
            s  += v.x + v.y + v.z + v.w;
            s2 += v.x * v.x + v.y * v.y + v.z * v.z + v.w * v.w;
        }
        s  += __shfl_xor(s, 1);
        s2 += __shfl_xor(s2, 1);
        if ((tid & 1) == 0) {
            float mu  = s * (1.0f / DIMM);
            float var = s2 * (1.0f / DIMM) - mu * mu;
            muS[r] = mu;
            rsS[r] = rsqrtf(var + 1e-5f);
        }
        lwS[tid] = lnw[tid];
        lbS[tid] = lnb[tid];
    }
    __syncthreads();

    floatx4 acc[4][4] = {};

    int ar = tid >> 1;
    int ak = (tid & 1) * 16;

    for (int k0 = 0; k0 < DIMM; k0 += GBK2) {
        {
            float mu = muS[ar], rs = rsS[ar];
            const float4* src = (const float4*)(x + (size_t)(m0 + ar) * DIMM + k0 + ak);
            unsigned short tmp[16];
#pragma unroll
            for (int q = 0; q < 4; ++q) {
                float4 v = src[q];
                int kk = k0 + ak + q * 4;
                tmp[q * 4 + 0] = f2bf((v.x - mu) * rs * lwS[kk + 0] + lbS[kk + 0]);
                tmp[q * 4 + 1] = f2bf((v.y - mu) * rs * lwS[kk + 1] + lbS[kk + 1]);
                tmp[q * 4 + 2] = f2bf((v.z - mu) * rs * lwS[kk + 2] + lbS[kk + 2]);
                tmp[q * 4 + 3] = f2bf((v.w - mu) * rs * lwS[kk + 3] + lbS[kk + 3]);
            }
            *(int4*)&As[ar * LDW2 + ak]     = *(const int4*)&tmp[0];
            *(int4*)&As[ar * LDW2 + ak + 8] = *(const int4*)&tmp[8];
        }
        {
            const unsigned short* src = &Bw[(size_t)(n0 + ar) * DIMM + k0 + ak];
            int4 b0 = *(const int4*)(src);
            int4 b1 = *(const int4*)(src + 8);
            *(int4*)&Bs[ar * LDW2 + ak]     = b0;
            *(int4*)&Bs[ar * LDW2 + ak + 8] = b1;
        }
        __syncthreads();
        short8 af[4], bf[4];
#pragma unroll
        for (int i = 0; i < 4; ++i)
            af[i] = *(const short8*)&As[(wm + i * 16 + lr) * LDW2 + quad * 8];
#pragma unroll
        for (int j = 0; j < 4; ++j)
            bf[j] = *(const short8*)&Bs[(wn + j * 16 + lr) * LDW2 + quad * 8];
#pragma unroll
        for (int i = 0; i < 4; ++i)
#pragma unroll
            for (int j = 0; j < 4; ++j)
                acc[i][j] = __builtin_amdgcn_mfma_f32_16x16x32_bf16(af[i], bf[j], acc[i][j], 0, 0, 0);
        __syncthreads();
    }

#pragma unroll
    for (int j = 0; j < 4; ++j) {
        int cn = n0 + wn + j * 16 + lr;
        float bb = bias[cn];
        unsigned short* dst = (cn < nsplit) ? C1b : C2b;
        int col = (cn < nsplit) ? cn : cn - nsplit;
#pragma unroll
        for (int i = 0; i < 4; ++i)
#pragma unroll
            for (int r = 0; r < 4; ++r) {
                int cm = m0 + wm + i * 16 + quad * 4 + r;
                dst[(size_t)cm * ldc + col] = f2bf(acc[i][j][r] + bb);
            }
    }
}

// ---------------- bf16 MFMA NT GEMM (generic, proven) ------------------------
#define TBM 128
#define TBN 64
#define TBK 32
#define LDKW (TBK + 8)
__global__ __launch_bounds__(256) void gemm_bf16(const unsigned short* __restrict__ A, int lda,
                                                 const unsigned short* __restrict__ Bw, int ldb,
                                                 const float* __restrict__ bias,
                                                 const float* __restrict__ resid,
                                                 float* __restrict__ C,
                                                 unsigned short* __restrict__ C1b,
                                                 unsigned short* __restrict__ C2b, int nsplit,
                                                 int ldc, int N, int K) {
    using short8  = __attribute__((ext_vector_type(8))) short;
    using floatx4 = __attribute__((ext_vector_type(4))) float;
    __shared__ __align__(16) unsigned short As[TBM * LDKW];
    __shared__ __align__(16) unsigned short Bs[TBN * LDKW];

    int tid  = threadIdx.x;
    int m0   = blockIdx.y * TBM;
    int n0   = blockIdx.x * TBN;
    int w    = tid >> 6;
    int lane = tid & 63;
    int wm   = (w & 1) * 64;
    int wn   = (w >> 1) * 32;
    int lr   = lane & 15;
    int quad = lane >> 4;

    floatx4 acc[4][2] = {};

    int ar = tid >> 1;
    int ak = (tid & 1) * 16;
    int br = tid >> 2;
    int bk = (tid & 3) * 8;

    for (int k0 = 0; k0 < K; k0 += TBK) {
        {
            const unsigned short* src = &A[(size_t)(m0 + ar) * lda + k0 + ak];
            int4 a0 = *(const int4*)(src);
            int4 a1 = *(const int4*)(src + 8);
            *(int4*)&As[ar * LDKW + ak]     = a0;
            *(int4*)&As[ar * LDKW + ak + 8] = a1;
        }
        {
            int gn = n0 + br;
            int4 b0 = make_int4(0, 0, 0, 0);
            if (gn < N) b0 = *(const int4*)&Bw[(size_t)gn * ldb + k0 + bk];
            *(int4*)&Bs[br * LDKW + bk] = b0;
        }
        __syncthreads();
        short8 af[4], bf[2];
#pragma unroll
        for (int i = 0; i < 4; ++i)
            af[i] = *(const short8*)&As[(wm + i * 16 + lr) * LDKW + quad * 8];
#pragma unroll
        for (int j = 0; j < 2; ++j)
            bf[j] = *(const short8*)&Bs[(wn + j * 16 + lr) * LDKW + quad * 8];
#pragma unroll
        for (int i = 0; i < 4; ++i)
#pragma unroll
            for (int j = 0; j < 2; ++j)
                acc[i][j] = __builtin_amdgcn_mfma_f32_16x16x32_bf16(af[i], bf[j], acc[i][j], 0, 0, 0);
        __syncthreads();
    }

#pragma unroll
    for (int j = 0; j < 2; ++j) {
        int cn = n0 + wn + j * 16 + lr;
        if (cn < N) {
            float bb = bias ? bias[cn] : 0.0f;
            if (C1b) {
                unsigned short* dst = (cn < nsplit) ? C1b : C2b;
                int col = (cn < nsplit) ? cn : cn - nsplit;
#pragma unroll
                for (int i = 0; i < 4; ++i)
#pragma unroll
                    for (int r = 0; r < 4; ++r) {
                        int cm = m0 + wm + i * 16 + quad * 4 + r;
                        dst[(size_t)cm * ldc + col] = f2bf(acc[i][j][r] + bb);
                    }
            } else {
#pragma unroll
                for (int i = 0; i < 4; ++i)
#pragma unroll
                    for (int r = 0; r < 4; ++r) {
                        int cm = m0 + wm + i * 16 + quad * 4 + r;
                        float v = acc[i][j][r] + bb;
                        if (resid) v += resid[(size_t)cm * ldc + cn];
                        C[(size_t)cm * ldc + cn] = v;
                    }
            }
        }
    }
}

// ---------------- Depthwise causal conv (4-tap) + SiLU, bf16 in/out ----------
__global__ __launch_bounds__(256) void conv_silu(const unsigned short* __restrict__ Xb,
                                                 const float* __restrict__ cw,
                                                 const float* __restrict__ cb,
                                                 unsigned short* __restrict__ xcb) {
    int idx = blockIdx.x * blockDim.x + threadIdx.x;
    int d = idx & (DIN - 1);
    int t = idx >> 9;
    int l = t & (LL - 1);
    int bq = t >> 9;
    float acc = cb[d];
#pragma unroll
    for (int k = 0; k < DCONV; ++k) {
        int ls = l - (DCONV - 1) + k;
        if (ls >= 0) acc += cw[d * DCONV + k] * bf2f(Xb[(size_t)(bq * LL + ls) * DIN + d]);
    }
    float v = acc / (1.0f + __expf(-acc));
    xcb[(size_t)t * DIN + d] = f2bf(v);
}

// ---------------- dt = softplus(dbc[:, :16] @ dtw^T + dtb) -> bf16 -----------
__global__ __launch_bounds__(256) void dt_kernel(const float* __restrict__ dbc,
                                                 const float* __restrict__ dtw,
                                                 const float* __restrict__ dtbias,
                                                 unsigned short* __restrict__ dtout) {
    int idx = blockIdx.x * blockDim.x + threadIdx.x;
    int d = idx & (DIN - 1);
    int t = idx >> 9;
    float a = dtbias[d];
    const float4* wv = (const float4*)(dtw + d * DTRANK);
    const float* dr = dbc + (size_t)t * DBC_DIM;
#pragma unroll
    for (int q = 0; q < 4; ++q) {
        float4 w4 = wv[q];
        a += w4.x * dr[q * 4 + 0] + w4.y * dr[q * 4 + 1] +
             w4.z * dr[q * 4 + 2] + w4.w * dr[q * 4 + 3];
    }
    float sp = (a > 20.0f) ? a : log1pf(__expf(a));
    dtout[(size_t)t * DIN + d] = f2bf(sp);
}

// ---------------- Selective scan: state-split (2 thr/d, 8 states each) -------
__global__ __launch_bounds__(256) void scan_p1(const unsigned short* __restrict__ xcb,
                                               const unsigned short* __restrict__ dtb,
                                               const float* __restrict__ dbc,
                                               const float* __restrict__ A_log,
                                               float* __restrict__ S,
                                               float* __restrict__ H) {
    int bid = blockIdx.x;
    int dq = bid & 3;
    int c  = (bid >> 2) & (NC - 1);
    int b  = bid >> 7;
    int dloc = threadIdx.x >> 1;
    int sh   = threadIdx.x & 1;
    int d  = dq * 128 + dloc;
    int n0 = sh * 8;
    int base = b * LL + c * CHUNK;

    __shared__ float LB[CHUNK * DBC_DIM];
    for (int i = threadIdx.x; i < CHUNK * DBC_DIM / 4; i += 256)
        ((float4*)LB)[i] = ((const float4*)(dbc + (size_t)base * DBC_DIM))[i];

    float a[8];
    {
        const float4* ar = (const float4*)(A_log + d * DSTATE + n0);
        float4 v0 = ar[0], v1 = ar[1];
        a[0] = -__expf(v0.x); a[1] = -__expf(v0.y); a[2] = -__expf(v0.z); a[3] = -__expf(v0.w);
        a[4] = -__expf(v1.x); a[5] = -__expf(v1.y); a[6] = -__expf(v1.z); a[7] = -__expf(v1.w);
    }
    __syncthreads();

    float h[8];
#pragma unroll
    for (int j = 0; j < 8; ++j) h[j] = 0.0f;
    float Ssum = 0.0f;
    float u   = bf2f(xcb[(size_t)base * DIN + d]);
    float dtv = bf2f(dtb[(size_t)base * DIN + d]);
#pragma unroll 4
    for (int s = 0; s < CHUNK; ++s) {
        float nu  = bf2f(xcb[(size_t)(base + s + 1) * DIN + d]);
        float ndt = bf2f(dtb[(size_t)(base + s + 1) * DIN + d]);
        const float* row = &LB[s * DBC_DIM];
        float4 b0 = *(const float4*)&row[DTRANK + n0];
        float4 b1 = *(const float4*)&row[DTRANK + n0 + 4];
        const float btv[8] = {b0.x, b0.y, b0.z, b0.w, b1.x, b1.y, b1.z, b1.w};
        Ssum += dtv;
        float wv = dtv * u;
#pragma unroll
        for (int j = 0; j < 8; ++j) {
            float dA = __expf(dtv * a[j]);
            h[j] = dA * h[j] + wv * btv[j];
        }
        u = nu; dtv = ndt;
    }
    size_t sc = (size_t)b * NC + c;
    if (sh == 0) S[sc * DIN + d] = Ssum;
#pragma unroll
    for (int j = 0; j < 8; ++j) H[(sc * DIN + d) * 16 + n0 + j] = h[j];
}

__global__ __launch_bounds__(256) void scan_p2(const float* __restrict__ A_log,
                                               const float* __restrict__ S,
                                               float* __restrict__ H) {
    int idx = blockIdx.x * 256 + threadIdx.x;   // BB*DIN*16
    int n = idx & 15;
    int d = (idx >> 4) & (DIN - 1);
    int b = idx >> 13;
    float a = -__expf(A_log[d * DSTATE + n]);
    float h = 0.0f;
#pragma unroll
    for (int c = 0; c < NC; ++c) {
        size_t sc = (size_t)b * NC + c;
        float Sv = S[sc * DIN + d];
        size_t q = (sc * DIN + d) * 16 + n;
        float Hc = H[q];
        H[q] = h;
        h = __expf(a * Sv) * h + Hc;
    }
}

__global__ __launch_bounds__(256) void scan_p3(const unsigned short* __restrict__ xcb,
                                               const unsigned short* __restrict__ dtb,
                                               const unsigned short* __restrict__ Zb,
                                               const float* __restrict__ dbc,
                                               const float* __restrict__ A_log,
                                               const float* __restrict__ Dp,
                                               const float* __restrict__ Hin,
                                               unsigned short* __restrict__ gb) {
    int bid = blockIdx.x;
    int dq = bid & 3;
    int c  = (bid >> 2) & (NC - 1);
    int b  = bid >> 7;
    int dloc = threadIdx.x >> 1;
    int sh   = threadIdx.x & 1;
    int d  = dq * 128 + dloc;
    int n0 = sh * 8;
    int base = b * LL + c * CHUNK;

    __shared__ float LB[CHUNK * DBC_DIM];
    for (int i = threadIdx.x; i < CHUNK * DBC_DIM / 4; i += 256)
        ((float4*)LB)[i] = ((const float4*)(dbc + (size_t)base * DBC_DIM))[i];

    float a[8];
    {
        const float4* ar = (const float4*)(A_log + d * DSTATE + n0);
        float4 v0 = ar[0], v1 = ar[1];
        a[0] = -__expf(v0.x); a[1] = -__expf(v0.y); a[2] = -__expf(v0.z); a[3] = -__expf(v0.w);
        a[4] = -__expf(v1.x); a[5] = -__expf(v1.y); a[6] = -__expf(v1.z); a[7] = -__expf(v1.w);
    }
    float Dd = Dp[d];
    size_t sc = (size_t)b * NC + c;
    float h[8];
#pragma unroll
    for (int j = 0; j < 8; ++j) h[j] = Hin[(sc * DIN + d) * 16 + n0 + j];
    __syncthreads();

    float u   = bf2f(xcb[(size_t)base * DIN + d]);
    float dtv = bf2f(dtb[(size_t)base * DIN + d]);
#pragma unroll 4
    for (int s = 0; s < CHUNK; ++s) {
        float nu  = bf2f(xcb[(size_t)(base + s + 1) * DIN + d]);
        float ndt = bf2f(dtb[(size_t)(base + s + 1) * DIN + d]);
        const float* row = &LB[s * DBC_DIM];
        float4 b0 = *(const float4*)&row[DTRANK + n0];
        float4 b1 = *(const float4*)&row[DTRANK + n0 + 4];
        float4 c0 = *(const float4*)&row[DTRANK + DSTATE + n0];
        float4 c1 = *(const float4*)&row[DTRANK + DSTATE + n0 + 4];
        const float btv[8] = {b0.x, b0.y, b0.z, b0.w, b1.x, b1.y, b1.z, b1.w};
        const float ctv[8] = {c0.x, c0.y, c0.z, c0.w, c1.x, c1.y, c1.z, c1.w};
        float wv = dtv * u;
        float y  = (sh == 0) ? u * Dd : 0.0f;
#pragma unroll
        for (int j = 0; j < 8; ++j) {
            float dA = __expf(dtv * a[j]);
            h[j] = dA * h[j] + wv * btv[j];
            y += h[j] * ctv[j];
        }
        y += __shfl_xor(y, 1);
        if (sh == 0) {
            float zf = bf2f(Zb[(size_t)(base + s) * DIN + d]);
            float g = y * (zf / (1.0f + __expf(-zf)));
            gb[(size_t)(base + s) * DIN + d] = f2bf(g);
        }
        u = nu; dtv = ndt;
    }
}

extern "C" void kernel_launch(void* const* d_in, const int* in_sizes, int n_in,
                              void* d_out, int out_size, void* d_ws, size_t ws_size,
                              hipStream_t stream) {
    const float* x_in   = (const float*)d_in[0];
    const float* ln_w   = (const float*)d_in[1];
    const float* ln_b   = (const float*)d_in[2];
    const float* in_w   = (const float*)d_in[3];
    const float* in_b   = (const float*)d_in[4];
    const float* conv_w = (const float*)d_in[5];
    const float* conv_b = (const float*)d_in[6];
    const float* xp_w   = (const float*)d_in[7];
    const float* dt_w   = (const float*)d_in[8];
    const float* dt_b   = (const float*)d_in[9];
    const float* A_log  = (const float*)d_in[10];
    const float* Dp     = (const float*)d_in[11];
    const float* ow     = (const float*)d_in[12];
    float* out = (float*)d_out;

    const size_t M = 1048576;
    float* ws = (float*)d_ws;
    float* xbuf = ws;                              // [0,2M) fp32 layer io
    float* dbc = ws + 3 * M;                       // [3M,3.5M) fp32 TT*48
    unsigned short* Xb  = (unsigned short*)(ws + 4 * M);   // [4M,6M) bf16 TT*512
    unsigned short* Zb  = (unsigned short*)(ws + 6 * M);   // [6M,8M)
    unsigned short* xcb = (unsigned short*)(ws + 8 * M);   // [8M,10M)
    unsigned short* dtb = (unsigned short*)(ws + 10 * M);  // [10M,12M)
    unsigned short* gb  = (unsigned short*)(ws + 12 * M);  // [12M,14M)
    float* Hbuf = ws + 14 * M;                     // [14M,18M) BB*NC*DIN*16 = 4M
    float* Sbuf = ws + 18 * M;                     // [18M,18.25M)
    unsigned short* inwb = (unsigned short*)(ws + 18 * M + 262144);
    unsigned short* owb  = inwb + (size_t)NB * XZ_DIM * DIMM;
    unsigned short* xpwb = owb + (size_t)NB * DIMM * DIN;

    cvt3_kernel<<<256, 256, 0, stream>>>(
        in_w, inwb, NB * XZ_DIM * DIMM / 4,
        ow,   owb,  NB * DIMM * DIN / 4,
        xp_w, xpwb, NB * DBC_DIM * DIN / 4);

    for (int layer = 0; layer < NB; ++layer) {
        const float* xi = (layer == 0) ? x_in : xbuf;
        float* xo = (layer == NB - 1) ? out : xbuf;

        // fused LN + in_proj: both halves bf16 (X -> Xb, Z -> Zb)
        ln_inproj<<<dim3(XZ_DIM / GBN2, TT / GBM2), 256, 0, stream>>>(
            xi, ln_w + layer * DIMM, ln_b + layer * DIMM,
            inwb + (size_t)layer * XZ_DIM * DIMM, in_b + layer * XZ_DIM,
            Xb, Zb, DIN, DIN);

        conv_silu<<<(TT * DIN) / 256, 256, 0, stream>>>(
            Xb, conv_w + layer * DIN * DCONV, conv_b + layer * DIN, xcb);

        // x_proj: bf16 MFMA -> dbc fp32
        gemm_bf16<<<dim3(1, TT / TBM), 256, 0, stream>>>(
            xcb, DIN, xpwb + (size_t)layer * DBC_DIM * DIN, DIN,
            nullptr, nullptr, dbc, nullptr, nullptr, 0, DBC_DIM, DBC_DIM, DIN);

        dt_kernel<<<(TT * DIN) / 256, 256, 0, stream>>>(
            dbc, dt_w + (size_t)layer * DIN * DTRANK, dt_b + layer * DIN, dtb);

        const float* Al = A_log + (size_t)layer * DIN * DSTATE;
        scan_p1<<<BB * NC * 4, 256, 0, stream>>>(xcb, dtb, dbc, Al, Sbuf, Hbuf);
        scan_p2<<<(BB * DIN * 16) / 256, 256, 0, stream>>>(Al, Sbuf, Hbuf);
        scan_p3<<<BB * NC * 4, 256, 0, stream>>>(xcb, dtb, Zb, dbc, Al,
                                                 Dp + layer * DIN, Hbuf, gb);

        // out_proj: fp32 out + residual
        gemm_bf16<<<dim3(DIMM / TBN, TT / TBM), 256, 0, stream>>>(
            gb, DIN, owb + (size_t)layer * DIMM * DIN, DIN,
            nullptr, xi, xo, nullptr, nullptr, 0, DIMM, DIMM, DIN);
    }
}